// Round 15
// baseline (969.623 us; speedup 1.0000x reference)
//
#include <hip/hip_runtime.h>
#include <math.h>

static constexpr int N = 8192;
static constexpr int M = 256;
static constexpr float SHIFT = 96.0f;

typedef __attribute__((ext_vector_type(8))) short bf16x8;
typedef __attribute__((ext_vector_type(4))) float f32x4;

__device__ __forceinline__ unsigned short f2bf(float x) {
  unsigned int u = __builtin_bit_cast(unsigned int, x);
  u += 0x7fffu + ((u >> 16) & 1u);
  return (unsigned short)(u >> 16);
}
__device__ __forceinline__ float bf2f(unsigned short h) {
  unsigned int u = ((unsigned int)h) << 16;
  return __builtin_bit_cast(float, u);
}
__device__ __forceinline__ f32x4 mfma16(bf16x8 a, bf16x8 b, f32x4 c) {
  return __builtin_amdgcn_mfma_f32_16x16x32_bf16(a, b, c, 0, 0, 0);
}
__device__ __forceinline__ bf16x8 ld8(const unsigned short* p) {
  return *reinterpret_cast<const bf16x8*>(p);
}
__device__ __forceinline__ bf16x8 lds8(const unsigned short* p) {
  return *reinterpret_cast<const bf16x8*>(p);
}
__device__ __forceinline__ void gl16(const unsigned short* g, unsigned short* ldsb) {
  __builtin_amdgcn_global_load_lds(
      (const __attribute__((address_space(1))) unsigned int*)g,
      (__attribute__((address_space(3))) unsigned int*)ldsb, 16, 0, 0);
}

// Packed fragment layout ("P"): for row-major S[R][C] (C multiple of 32),
// granule (rb, cg) holds lane l, elem e: S[rb*16 + (l&15)][cg*32 + (l>>4)*8 + e]
// short offset = ((rb*(C/32) + cg)*64 + l)*8 + e.

// ---------------------------------------------------------------------------
__global__ void zero_f32(float* __restrict__ p, int n4) {
  int i = blockIdx.x * 256 + threadIdx.x;
  if (i < n4) reinterpret_cast<float4*>(p)[i] = float4{0.f, 0.f, 0.f, 0.f};
}

// ---------------------------------------------------------------------------
// Ap = audio @ W^T. Writes hi+lo both in packed layout (C=256).
// ---------------------------------------------------------------------------
__global__ __launch_bounds__(256) void gemm_ap(const float* __restrict__ A,
                                               const float* __restrict__ B,
                                               unsigned short* __restrict__ ChP,
                                               unsigned short* __restrict__ ClP) {
  __shared__ float As[32 * 68];
  __shared__ float Bs[32 * 68];
  const int tid = threadIdx.x;
  const int ty = tid >> 4, tx = tid & 15;
  const int row0 = blockIdx.x * 64, col0 = blockIdx.y * 64;
  float acc[4][4] = {};
  for (int k0 = 0; k0 < M; k0 += 32) {
#pragma unroll
    for (int l = 0; l < 8; ++l) {
      int idx = tid + l * 256;
      int r = idx >> 5, c = idx & 31;
      As[c * 68 + r] = A[(size_t)(row0 + r) * M + k0 + c];
      Bs[c * 68 + r] = B[(size_t)(col0 + r) * M + k0 + c];
    }
    __syncthreads();
#pragma unroll
    for (int kk = 0; kk < 32; ++kk) {
      float4 a = *(const float4*)(As + kk * 68 + ty * 4);
      float4 b = *(const float4*)(Bs + kk * 68 + tx * 4);
      float av[4] = {a.x, a.y, a.z, a.w}, bv[4] = {b.x, b.y, b.z, b.w};
#pragma unroll
      for (int r = 0; r < 4; ++r)
#pragma unroll
        for (int c = 0; c < 4; ++c) acc[r][c] = fmaf(av[r], bv[c], acc[r][c]);
    }
    __syncthreads();
  }
#pragma unroll
  for (int r = 0; r < 4; ++r)
#pragma unroll
    for (int c = 0; c < 4; ++c) {
      float x = acc[r][c];
      unsigned short h = f2bf(x);
      int i = row0 + ty * 4 + r, k = col0 + tx * 4 + c;
      size_t off = ((size_t)(i >> 4) * 8 + (k >> 5)) * 512 +
                   ((((k >> 3) & 3) * 16) + (i & 15)) * 8 + (k & 7);
      ChP[off] = h;
      ClP[off] = f2bf(x - bf2f(h));
    }
}

// ---------------------------------------------------------------------------
// Split/transpose: optional rhP/rlP packed (row-major, C=256);
// thP/tlP packed transposed (rows=M coords, C=8192).
// ---------------------------------------------------------------------------
__global__ __launch_bounds__(256) void trsplit(const float* __restrict__ src,
                                               unsigned short* rhP,
                                               unsigned short* rlP,
                                               unsigned short* __restrict__ thP,
                                               unsigned short* __restrict__ tlP) {
  __shared__ float T[64][65];
  const int i0 = blockIdx.x * 64, m0 = blockIdx.y * 64;
  const int tid = threadIdx.x;
#pragma unroll
  for (int s = 0; s < 2; ++s) {
    int idx = tid + s * 256;
    int r = idx >> 3, ch = idx & 7;
    float v[8];
    float4 x0 = *(const float4*)(src + (size_t)(i0 + r) * M + m0 + ch * 8);
    float4 x1 = *(const float4*)(src + (size_t)(i0 + r) * M + m0 + ch * 8 + 4);
    v[0] = x0.x; v[1] = x0.y; v[2] = x0.z; v[3] = x0.w;
    v[4] = x1.x; v[5] = x1.y; v[6] = x1.z; v[7] = x1.w;
#pragma unroll
    for (int e = 0; e < 8; ++e) T[r][ch * 8 + e] = v[e];
    if (rhP != nullptr) {
      bf16x8 h8, l8;
#pragma unroll
      for (int e = 0; e < 8; ++e) {
        unsigned short h = f2bf(v[e]);
        h8[e] = (short)h;
        l8[e] = (short)f2bf(v[e] - bf2f(h));
      }
      size_t off = ((size_t)((i0 + r) >> 4) * 8 + (m0 >> 5) + (ch >> 2)) * 512 +
                   ((ch & 3) * 16 + (r & 15)) * 8;
      *(bf16x8*)(rhP + off) = h8;
      *(bf16x8*)(rlP + off) = l8;
    }
  }
  __syncthreads();
#pragma unroll
  for (int s = 0; s < 2; ++s) {
    int idx = tid + s * 256;
    int r = idx >> 3, c8 = idx & 7;  // out row m0+r, cols i0 + c8*8 ..
    bf16x8 h8, l8;
#pragma unroll
    for (int e = 0; e < 8; ++e) {
      float x = T[c8 * 8 + e][r];
      unsigned short h = f2bf(x);
      h8[e] = (short)h;
      l8[e] = (short)f2bf(x - bf2f(h));
    }
    size_t off = ((size_t)((m0 + r) >> 4) * 256 + (i0 >> 5) + (c8 >> 2)) * 512 +
                 ((c8 & 3) * 16 + (r & 15)) * 8;
    *(bf16x8*)(thP + off) = h8;
    *(bf16x8*)(tlP + off) = l8;
  }
}

// ---------------------------------------------------------------------------
// Stats: V-hi tile staged (packed, conflict-free); V-lo + Ap h/l packed global.
// ---------------------------------------------------------------------------
__global__ __launch_bounds__(512, 4) void stats_mfma(
    const unsigned short* __restrict__ AphP, const unsigned short* __restrict__ AplP,
    const unsigned short* __restrict__ VhP, const unsigned short* __restrict__ VlP,
    float* __restrict__ rps, float* __restrict__ cps) {
  __shared__ unsigned short Vsh[16384];  // 32 granules
  __shared__ float cred[8][64];
  const int tid = threadIdx.x;
  const int w = tid >> 6, l = tid & 63;
  const int lm = l & 15, lk = l >> 4;
  const int b = blockIdx.x;
  const int p = b >> 4, q = b & 15;

  bf16x8 ah[8];
#pragma unroll
  for (int kk = 0; kk < 8; ++kk)
    ah[kk] = ld8(AphP + ((size_t)(p * 8 + w) * 8 + kk) * 512 + l * 8);
  const unsigned short* alp = AplP + (size_t)(p * 8 + w) * 8 * 512 + l * 8;

  float rsum[4] = {0.f, 0.f, 0.f, 0.f};

  for (int jt = 0; jt < 8; ++jt) {
    const int j0 = q * 512 + jt * 64;
    const size_t gbV = (size_t)(j0 >> 4) * 8 * 512;
#pragma unroll
    for (int s = 0; s < 4; ++s) {
      int u = tid + s * 512;
      *(bf16x8*)(Vsh + u * 8) = ld8(VhP + gbV + u * 8);
    }
    __syncthreads();

    f32x4 acc[4];
#pragma unroll
    for (int js = 0; js < 4; ++js) acc[js] = f32x4{0.f, 0.f, 0.f, 0.f};
#pragma unroll
    for (int kk = 0; kk < 8; ++kk) {
      bf16x8 alv = ld8(alp + kk * 512);
#pragma unroll
      for (int js = 0; js < 4; ++js) {
        bf16x8 bh = lds8(Vsh + (js * 8 + kk) * 512 + l * 8);
        bf16x8 bl = ld8(VlP + ((size_t)((j0 >> 4) + js) * 8 + kk) * 512 + l * 8);
        acc[js] = mfma16(ah[kk], bh, acc[js]);
        acc[js] = mfma16(ah[kk], bl, acc[js]);
        acc[js] = mfma16(alv, bh, acc[js]);
      }
    }
#pragma unroll
    for (int js = 0; js < 4; ++js) {
      float e0 = __expf(acc[js][0] - SHIFT), e1 = __expf(acc[js][1] - SHIFT);
      float e2 = __expf(acc[js][2] - SHIFT), e3 = __expf(acc[js][3] - SHIFT);
      rsum[0] += e0; rsum[1] += e1; rsum[2] += e2; rsum[3] += e3;
      float c = e0 + e1 + e2 + e3;
      c += __shfl_xor(c, 16);
      c += __shfl_xor(c, 32);
      if (lk == 0) cred[w][js * 16 + lm] = c;
    }
    __syncthreads();
    if (tid < 64) {
      float c = 0.f;
#pragma unroll
      for (int ww = 0; ww < 8; ++ww) c += cred[ww][tid];
      cps[(size_t)p * N + j0 + tid] = c;
    }
    __syncthreads();
  }
#pragma unroll
  for (int r = 0; r < 4; ++r) {
    float s = rsum[r];
    s += __shfl_xor(s, 1);
    s += __shfl_xor(s, 2);
    s += __shfl_xor(s, 4);
    s += __shfl_xor(s, 8);
    if (lm == 0) rps[(size_t)q * N + p * 128 + w * 16 + lk * 4 + r] = s;
  }
}

__global__ void row_inv(const float* __restrict__ rps, float* __restrict__ rinv) {
  int i = blockIdx.x * 256 + threadIdx.x;
  float s = 0.f;
#pragma unroll
  for (int q = 0; q < 16; ++q) s += rps[(size_t)q * N + i];
  rinv[i] = 1.f / s;
}
__global__ void col_inv(const float* __restrict__ cps, float* __restrict__ cinv) {
  int j = blockIdx.x * 256 + threadIdx.x;
  float s = 0.f;
  for (int p = 0; p < 64; ++p) s += cps[(size_t)p * N + j];
  cinv[j] = 1.f / s;
}

// ---------------------------------------------------------------------------
// out_audio: d_audio[i,m] = sum_j E(corr[i,j])*cinv[j]*audio[j,m].
// 1024 threads (16 waves), i-panel 128, j-tile 64, LDS 160 KB, 1 blk/CU.
// corr wave (ipair=w&3, jsub=w>>2): 2 i-subs share each B read; A-hi regs,
// A-lo global packed (loop-invariant, L1/L2-hot).
// weighted wave (ipair=w&3, mquad=w>>2): 2 i-subs x 4 m-granules x 2 jg.
// ---------------------------------------------------------------------------
__global__ __launch_bounds__(1024, 4) void out_audio_p(
    const unsigned short* __restrict__ AphP, const unsigned short* __restrict__ AplP,
    const unsigned short* __restrict__ VhP, const unsigned short* __restrict__ VlP,
    const unsigned short* __restrict__ AuThP, const unsigned short* __restrict__ AuTlP,
    const float* __restrict__ cinv, float* __restrict__ out) {
  __shared__ unsigned short Vsh[16384];  // V tile [64j][256k] hi: 32 granules
  __shared__ unsigned short Vsl[16384];
  __shared__ unsigned short Ath[16384];  // AuT tile [256m][64j] hi: 32 granules
  __shared__ unsigned short Atl[16384];
  __shared__ unsigned short Wah[8192];   // W [128i][64j]: 16 granules
  __shared__ unsigned short Wal[8192];

  const int tid = threadIdx.x;
  const int w = tid >> 6, l = tid & 63;
  const int lm = l & 15, lk = l >> 4;
  const int i0 = blockIdx.x * 128;
  const int jc = blockIdx.y;  // 4 chunks of 2048
  const int ipair = w & 3;
  const int jsub = w >> 2;   // corr j-sub (0..3)
  const int mquad = w >> 2;  // weighted m-quad (0..3)

  // A-hi fragments for 2 i-subs, loop-invariant: 64 VGPR. A-lo via global.
  bf16x8 ah[2][8];
  size_t ab[2];
#pragma unroll
  for (int is2 = 0; is2 < 2; ++is2) {
    ab[is2] = (size_t)((i0 >> 4) + ipair * 2 + is2) * 8 * 512 + l * 8;
#pragma unroll
    for (int kk = 0; kk < 8; ++kk) ah[is2][kk] = ld8(AphP + ab[is2] + kk * 512);
  }

  f32x4 dacc[2][4];
#pragma unroll
  for (int is2 = 0; is2 < 2; ++is2)
#pragma unroll
    for (int ms = 0; ms < 4; ++ms) dacc[is2][ms] = f32x4{0.f, 0.f, 0.f, 0.f};

  auto issue_V = [&](int j0) {
    const size_t gbV = (size_t)(j0 >> 4) * 8 * 512;
#pragma unroll
    for (int s = 0; s < 2; ++s) {
      int g = w * 2 + s;  // 32 granules over 16 waves
      gl16(VhP + gbV + (g * 64 + l) * 8, Vsh + g * 512);
      gl16(VlP + gbV + (g * 64 + l) * 8, Vsl + g * 512);
    }
  };
  auto issue_T = [&](int j0) {
#pragma unroll
    for (int s = 0; s < 2; ++s) {
      int u = w * 2 + s;
      int mg = u >> 1, jg = u & 1;
      size_t srcT = ((size_t)(mg * 256 + (j0 >> 5) + jg)) * 512 + l * 8;
      gl16(AuThP + srcT, Ath + u * 512);
      gl16(AuTlP + srcT, Atl + u * 512);
    }
  };

  issue_V(jc * 2048);
  issue_T(jc * 2048);

  for (int jt = 0; jt < 32; ++jt) {
    const int j0 = jc * 2048 + jt * 64;
    asm volatile("s_waitcnt vmcnt(0)" ::: "memory");
    __syncthreads();  // B1: tiles staged
    // ---- corr: 2 i-subs x 1 j-sub, 3-term ----
    f32x4 cc0 = f32x4{0.f, 0.f, 0.f, 0.f};
    f32x4 cc1 = f32x4{0.f, 0.f, 0.f, 0.f};
#pragma unroll
    for (int kk = 0; kk < 8; ++kk) {
      bf16x8 bh = lds8(Vsh + (jsub * 8 + kk) * 512 + l * 8);
      bf16x8 bl = lds8(Vsl + (jsub * 8 + kk) * 512 + l * 8);
      bf16x8 al0 = ld8(AplP + ab[0] + kk * 512);
      bf16x8 al1 = ld8(AplP + ab[1] + kk * 512);
      cc0 = mfma16(ah[0][kk], bh, cc0);
      cc0 = mfma16(ah[0][kk], bl, cc0);
      cc0 = mfma16(al0, bh, cc0);
      cc1 = mfma16(ah[1][kk], bh, cc1);
      cc1 = mfma16(ah[1][kk], bl, cc1);
      cc1 = mfma16(al1, bh, cc1);
    }
    // ---- W[i_loc][j_loc64] = E*cinv[j] -> packed LDS ----
    {
      float ci = cinv[j0 + jsub * 16 + lm];
      const int kap_hi = ((jsub & 1) * 2 + (lm >> 3)) * 16;  // (kappa>>3)*16
      const int kap_lo = lm & 7;
#pragma unroll
      for (int is2 = 0; is2 < 2; ++is2) {
        int g = (ipair * 2 + is2) * 2 + (jsub >> 1);
        f32x4 cc = is2 ? cc1 : cc0;
#pragma unroll
        for (int r = 0; r < 4; ++r) {
          float e = __expf(cc[r] - SHIFT) * ci;
          unsigned short h = f2bf(e);
          size_t off = (size_t)g * 512 + (size_t)(kap_hi + lk * 4 + r) * 8 + kap_lo;
          Wah[off] = h;
          Wal[off] = f2bf(e - bf2f(h));
        }
      }
    }
    __syncthreads();  // B2: W ready; V reads done
    if (jt + 1 < 32) issue_V(j0 + 64);
    // ---- weighted: 2 i-subs x 4 m-granules x 2 j-halves, 3-term ----
#pragma unroll
    for (int jg = 0; jg < 2; ++jg) {
      bf16x8 wh[2], wl[2];
#pragma unroll
      for (int is2 = 0; is2 < 2; ++is2) {
        size_t wo = (size_t)((ipair * 2 + is2) * 2 + jg) * 512 + l * 8;
        wh[is2] = lds8(Wah + wo);
        wl[is2] = lds8(Wal + wo);
      }
#pragma unroll
      for (int ms = 0; ms < 4; ++ms) {
        int u = (mquad * 4 + ms) * 2 + jg;
        bf16x8 vh8 = lds8(Ath + u * 512 + l * 8);
        bf16x8 vl8 = lds8(Atl + u * 512 + l * 8);
#pragma unroll
        for (int is2 = 0; is2 < 2; ++is2) {
          dacc[is2][ms] = mfma16(wh[is2], vh8, dacc[is2][ms]);
          dacc[is2][ms] = mfma16(wh[is2], vl8, dacc[is2][ms]);
          dacc[is2][ms] = mfma16(wl[is2], vh8, dacc[is2][ms]);
        }
      }
    }
    __syncthreads();  // B3: value reads done
    if (jt + 1 < 32) issue_T(j0 + 64);
  }
#pragma unroll
  for (int is2 = 0; is2 < 2; ++is2)
#pragma unroll
    for (int ms = 0; ms < 4; ++ms)
#pragma unroll
      for (int r = 0; r < 4; ++r) {
        int i = i0 + (ipair * 2 + is2) * 16 + lk * 4 + r;
        int m = (mquad * 4 + ms) * 16 + lm;
        atomicAdd(out + (size_t)i * (2 * M) + M + m, dacc[is2][ms][r]);
      }
}

// ---------------------------------------------------------------------------
// out_video: d_video[i,m] = sum_j E(corr[j,i])*rinv[j]*video[j,m].
// corr[j][i]: A = Ap[j-tile 64] (LDS h+l), B = video[i-panel 128]:
// hi hoisted regs for 2 i-subs, lo global packed (loop-invariant).
// corr wave (ipair=w&3, jsub=w>>2); weighted wave (ipair, mquad) as audio.
// ---------------------------------------------------------------------------
__global__ __launch_bounds__(1024, 4) void out_video_p(
    const unsigned short* __restrict__ AphP, const unsigned short* __restrict__ AplP,
    const unsigned short* __restrict__ VhP, const unsigned short* __restrict__ VlP,
    const unsigned short* __restrict__ ViThP, const unsigned short* __restrict__ ViTlP,
    const float* __restrict__ rinv, float* __restrict__ out) {
  __shared__ unsigned short Ash[16384];  // Ap tile [64j][256k] hi
  __shared__ unsigned short Asl[16384];
  __shared__ unsigned short Vts[16384];  // ViT tile [256m][64j] hi
  __shared__ unsigned short Vtl[16384];
  __shared__ unsigned short Wvh[8192];   // W_v [128i][64j]
  __shared__ unsigned short Wvl[8192];

  const int tid = threadIdx.x;
  const int w = tid >> 6, l = tid & 63;
  const int lm = l & 15, lk = l >> 4;
  const int i0 = blockIdx.x * 128;
  const int jc = blockIdx.y;
  const int ipair = w & 3;
  const int jsub = w >> 2;
  const int mquad = w >> 2;

  // video-panel B-fragments: hi hoisted for 2 i-subs (64 VGPR), lo global
  bf16x8 vph[2][8];
  size_t vb[2];
#pragma unroll
  for (int is2 = 0; is2 < 2; ++is2) {
    vb[is2] = (size_t)((i0 >> 4) + ipair * 2 + is2) * 8 * 512 + l * 8;
#pragma unroll
    for (int kk = 0; kk < 8; ++kk) vph[is2][kk] = ld8(VhP + vb[is2] + kk * 512);
  }

  f32x4 dacc[2][4];
#pragma unroll
  for (int is2 = 0; is2 < 2; ++is2)
#pragma unroll
    for (int ms = 0; ms < 4; ++ms) dacc[is2][ms] = f32x4{0.f, 0.f, 0.f, 0.f};

  auto issue_A = [&](int j0) {
    const size_t gbA = (size_t)(j0 >> 4) * 8 * 512;
#pragma unroll
    for (int s = 0; s < 2; ++s) {
      int g = w * 2 + s;
      gl16(AphP + gbA + (g * 64 + l) * 8, Ash + g * 512);
      gl16(AplP + gbA + (g * 64 + l) * 8, Asl + g * 512);
    }
  };
  auto issue_T = [&](int j0) {
#pragma unroll
    for (int s = 0; s < 2; ++s) {
      int u = w * 2 + s;
      int mg = u >> 1, jg = u & 1;
      size_t srcT = ((size_t)(mg * 256 + (j0 >> 5) + jg)) * 512 + l * 8;
      gl16(ViThP + srcT, Vts + u * 512);
      gl16(ViTlP + srcT, Vtl + u * 512);
    }
  };

  issue_A(jc * 2048);
  issue_T(jc * 2048);

  for (int jt = 0; jt < 32; ++jt) {
    const int j0 = jc * 2048 + jt * 64;
    asm volatile("s_waitcnt vmcnt(0)" ::: "memory");
    __syncthreads();  // B1
    // ---- corr[j=j0+jsub*16+lk*4+r][i-subs ipair*2..+1], 3-term ----
    f32x4 cc0 = f32x4{0.f, 0.f, 0.f, 0.f};
    f32x4 cc1 = f32x4{0.f, 0.f, 0.f, 0.f};
#pragma unroll
    for (int kk = 0; kk < 8; ++kk) {
      bf16x8 ahf = lds8(Ash + (jsub * 8 + kk) * 512 + l * 8);
      bf16x8 alf = lds8(Asl + (jsub * 8 + kk) * 512 + l * 8);
      bf16x8 vl0 = ld8(VlP + vb[0] + kk * 512);
      bf16x8 vl1 = ld8(VlP + vb[1] + kk * 512);
      cc0 = mfma16(ahf, vph[0][kk], cc0);
      cc0 = mfma16(ahf, vl0, cc0);
      cc0 = mfma16(alf, vph[0][kk], cc0);
      cc1 = mfma16(ahf, vph[1][kk], cc1);
      cc1 = mfma16(ahf, vl1, cc1);
      cc1 = mfma16(alf, vph[1][kk], cc1);
    }
    // ---- W_v[i_loc][j_loc64] = E(corr[j][i])*rinv[j] -> packed LDS ----
    {
#pragma unroll
      for (int is2 = 0; is2 < 2; ++is2) {
        f32x4 cc = is2 ? cc1 : cc0;
#pragma unroll
        for (int r = 0; r < 4; ++r) {
          int t = lk * 4 + r;                 // low 4 bits of j within sub
          float e = __expf(cc[r] - SHIFT) * rinv[j0 + jsub * 16 + t];
          unsigned short h = f2bf(e);
          int g = (ipair * 2 + is2) * 2 + (jsub >> 1);
          int kap32 = (jsub & 1) * 16 + t;    // j within 32-col granule
          size_t off = (size_t)g * 512 +
                       (size_t)((kap32 >> 3) * 16 + lm) * 8 + (kap32 & 7);
          Wvh[off] = h;
          Wvl[off] = f2bf(e - bf2f(h));
        }
      }
    }
    __syncthreads();  // B2
    if (jt + 1 < 32) issue_A(j0 + 64);
    // ---- weighted: 2 i-subs x 4 m-granules x 2 jg, 3-term ----
#pragma unroll
    for (int jg = 0; jg < 2; ++jg) {
      bf16x8 wh[2], wl[2];
#pragma unroll
      for (int is2 = 0; is2 < 2; ++is2) {
        size_t wo = (size_t)((ipair * 2 + is2) * 2 + jg) * 512 + l * 8;
        wh[is2] = lds8(Wvh + wo);
        wl[is2] = lds8(Wvl + wo);
      }
#pragma unroll
      for (int ms = 0; ms < 4; ++ms) {
        int u = (mquad * 4 + ms) * 2 + jg;
        bf16x8 vh8 = lds8(Vts + u * 512 + l * 8);
        bf16x8 vl8 = lds8(Vtl + u * 512 + l * 8);
#pragma unroll
        for (int is2 = 0; is2 < 2; ++is2) {
          dacc[is2][ms] = mfma16(wh[is2], vh8, dacc[is2][ms]);
          dacc[is2][ms] = mfma16(wh[is2], vl8, dacc[is2][ms]);
          dacc[is2][ms] = mfma16(wl[is2], vh8, dacc[is2][ms]);
        }
      }
    }
    __syncthreads();  // B3
    if (jt + 1 < 32) issue_T(j0 + 64);
  }
#pragma unroll
  for (int is2 = 0; is2 < 2; ++is2)
#pragma unroll
    for (int ms = 0; ms < 4; ++ms)
#pragma unroll
      for (int r = 0; r < 4; ++r) {
        int i = i0 + (ipair * 2 + is2) * 16 + lk * 4 + r;
        int m = (mquad * 4 + ms) * 16 + lm;
        atomicAdd(out + (size_t)i * (2 * M) + m, dacc[is2][ms][r]);
      }
}

// ---------------------------------------------------------------------------
__global__ void epilogue(float* __restrict__ out, const float* __restrict__ video,
                         const float* __restrict__ audio) {
  int idx = blockIdx.x * 256 + threadIdx.x;
  int i = idx >> 7;
  int c4 = idx & 127;
  float4 o = reinterpret_cast<float4*>(out)[(size_t)i * 128 + c4];
  const float* res = (c4 < 64) ? (video + (size_t)i * M + c4 * 4)
                               : (audio + (size_t)i * M + (c4 - 64) * 4);
  float4 rv = *reinterpret_cast<const float4*>(res);
  o.x = tanhf(o.x + rv.x);
  o.y = tanhf(o.y + rv.y);
  o.z = tanhf(o.z + rv.z);
  o.w = tanhf(o.w + rv.w);
  reinterpret_cast<float4*>(out)[(size_t)i * 128 + c4] = o;
}

// ---------------------------------------------------------------------------
extern "C" void kernel_launch(void* const* d_in, const int* in_sizes, int n_in,
                              void* d_out, int out_size, void* d_ws, size_t ws_size,
                              hipStream_t stream) {
  const float* audio = (const float*)d_in[0];
  const float* video = (const float*)d_in[1];
  const float* W = (const float*)d_in[2];
  float* out = (float*)d_out;

  const size_t nBF = (size_t)N * M * sizeof(unsigned short);  // 4 MB
  char* base = (char*)d_ws;
  unsigned short* AphP = (unsigned short*)(base);
  unsigned short* AplP = (unsigned short*)(base + 1 * nBF);
  unsigned short* VhP = (unsigned short*)(base + 2 * nBF);
  unsigned short* VlP = (unsigned short*)(base + 3 * nBF);
  unsigned short* ViThP = (unsigned short*)(base + 4 * nBF);
  unsigned short* ViTlP = (unsigned short*)(base + 5 * nBF);
  unsigned short* AuThP = (unsigned short*)(base + 6 * nBF);
  unsigned short* AuTlP = (unsigned short*)(base + 7 * nBF);
  float* rps = (float*)(base + 8 * nBF);   // 16*N
  float* cps = rps + 16 * (size_t)N;       // 64*N
  float* rinv = cps + 64 * (size_t)N;      // N
  float* cinv = rinv + N;                  // N
  const size_t need = 8 * nBF + (82 * (size_t)N) * sizeof(float);
  if (ws_size < need) return;

  zero_f32<<<dim3((N * 2 * M / 4 + 255) / 256), 256, 0, stream>>>(out, N * 2 * M / 4);
  gemm_ap<<<dim3(N / 64, M / 64), 256, 0, stream>>>(audio, W, AphP, AplP);
  trsplit<<<dim3(N / 64, M / 64), 256, 0, stream>>>(video, VhP, VlP, ViThP, ViTlP);
  trsplit<<<dim3(N / 64, M / 64), 256, 0, stream>>>(audio, nullptr, nullptr, AuThP, AuTlP);
  stats_mfma<<<1024, 512, 0, stream>>>(AphP, AplP, VhP, VlP, rps, cps);
  row_inv<<<N / 256, 256, 0, stream>>>(rps, rinv);
  col_inv<<<N / 256, 256, 0, stream>>>(cps, cinv);
  out_audio_p<<<dim3(N / 128, 4), 1024, 0, stream>>>(AphP, AplP, VhP, VlP,
                                                     AuThP, AuTlP, cinv, out);
  out_video_p<<<dim3(N / 128, 4), 1024, 0, stream>>>(AphP, AplP, VhP, VlP,
                                                     ViThP, ViTlP, rinv, out);
  epilogue<<<dim3(N * 2 * M / 4 / 256), 256, 0, stream>>>(out, video, audio);
}

// Round 16
// 635.823 us; speedup vs baseline: 1.5250x; 1.5250x over previous
//
#include <hip/hip_runtime.h>
#include <math.h>

static constexpr int N = 8192;
static constexpr int M = 256;
static constexpr float SHIFT = 96.0f;

typedef __attribute__((ext_vector_type(8))) short bf16x8;
typedef __attribute__((ext_vector_type(4))) float f32x4;

__device__ __forceinline__ unsigned short f2bf(float x) {
  unsigned int u = __builtin_bit_cast(unsigned int, x);
  u += 0x7fffu + ((u >> 16) & 1u);
  return (unsigned short)(u >> 16);
}
__device__ __forceinline__ float bf2f(unsigned short h) {
  unsigned int u = ((unsigned int)h) << 16;
  return __builtin_bit_cast(float, u);
}
__device__ __forceinline__ f32x4 mfma16(bf16x8 a, bf16x8 b, f32x4 c) {
  return __builtin_amdgcn_mfma_f32_16x16x32_bf16(a, b, c, 0, 0, 0);
}
__device__ __forceinline__ bf16x8 ld8(const unsigned short* p) {
  return *reinterpret_cast<const bf16x8*>(p);
}
__device__ __forceinline__ bf16x8 lds8(const unsigned short* p) {
  return *reinterpret_cast<const bf16x8*>(p);
}
// async global->LDS, 16B per lane; LDS dest = wave-uniform base + lane*16.
__device__ __forceinline__ void gl16(const unsigned short* g, unsigned short* ldsb) {
  __builtin_amdgcn_global_load_lds(
      (const __attribute__((address_space(1))) unsigned int*)g,
      (__attribute__((address_space(3))) unsigned int*)ldsb, 16, 0, 0);
}

// Packed fragment layout ("P"): for row-major S[R][C] (C multiple of 32),
// granule (rb, cg) holds lane l, elem e: S[rb*16 + (l&15)][cg*32 + (l>>4)*8 + e]
// short offset = ((rb*(C/32) + cg)*64 + l)*8 + e.

// ---------------------------------------------------------------------------
__global__ void zero_f32(float* __restrict__ p, int n4) {
  int i = blockIdx.x * 256 + threadIdx.x;
  if (i < n4) reinterpret_cast<float4*>(p)[i] = float4{0.f, 0.f, 0.f, 0.f};
}

// ---------------------------------------------------------------------------
// Ap = audio @ W^T. Writes hi+lo both in packed layout (C=256).
// ---------------------------------------------------------------------------
__global__ __launch_bounds__(256) void gemm_ap(const float* __restrict__ A,
                                               const float* __restrict__ B,
                                               unsigned short* __restrict__ ChP,
                                               unsigned short* __restrict__ ClP) {
  __shared__ float As[32 * 68];
  __shared__ float Bs[32 * 68];
  const int tid = threadIdx.x;
  const int ty = tid >> 4, tx = tid & 15;
  const int row0 = blockIdx.x * 64, col0 = blockIdx.y * 64;
  float acc[4][4] = {};
  for (int k0 = 0; k0 < M; k0 += 32) {
#pragma unroll
    for (int l = 0; l < 8; ++l) {
      int idx = tid + l * 256;
      int r = idx >> 5, c = idx & 31;
      As[c * 68 + r] = A[(size_t)(row0 + r) * M + k0 + c];
      Bs[c * 68 + r] = B[(size_t)(col0 + r) * M + k0 + c];
    }
    __syncthreads();
#pragma unroll
    for (int kk = 0; kk < 32; ++kk) {
      float4 a = *(const float4*)(As + kk * 68 + ty * 4);
      float4 b = *(const float4*)(Bs + kk * 68 + tx * 4);
      float av[4] = {a.x, a.y, a.z, a.w}, bv[4] = {b.x, b.y, b.z, b.w};
#pragma unroll
      for (int r = 0; r < 4; ++r)
#pragma unroll
        for (int c = 0; c < 4; ++c) acc[r][c] = fmaf(av[r], bv[c], acc[r][c]);
    }
    __syncthreads();
  }
#pragma unroll
  for (int r = 0; r < 4; ++r)
#pragma unroll
    for (int c = 0; c < 4; ++c) {
      float x = acc[r][c];
      unsigned short h = f2bf(x);
      int i = row0 + ty * 4 + r, k = col0 + tx * 4 + c;
      size_t off = ((size_t)(i >> 4) * 8 + (k >> 5)) * 512 +
                   ((((k >> 3) & 3) * 16) + (i & 15)) * 8 + (k & 7);
      ChP[off] = h;
      ClP[off] = f2bf(x - bf2f(h));
    }
}

// ---------------------------------------------------------------------------
// Split/transpose: optional rhP/rlP packed (row-major, C=256);
// thP/tlP packed transposed (rows=M coords, C=8192).
// ---------------------------------------------------------------------------
__global__ __launch_bounds__(256) void trsplit(const float* __restrict__ src,
                                               unsigned short* rhP,
                                               unsigned short* rlP,
                                               unsigned short* __restrict__ thP,
                                               unsigned short* __restrict__ tlP) {
  __shared__ float T[64][65];
  const int i0 = blockIdx.x * 64, m0 = blockIdx.y * 64;
  const int tid = threadIdx.x;
#pragma unroll
  for (int s = 0; s < 2; ++s) {
    int idx = tid + s * 256;
    int r = idx >> 3, ch = idx & 7;
    float v[8];
    float4 x0 = *(const float4*)(src + (size_t)(i0 + r) * M + m0 + ch * 8);
    float4 x1 = *(const float4*)(src + (size_t)(i0 + r) * M + m0 + ch * 8 + 4);
    v[0] = x0.x; v[1] = x0.y; v[2] = x0.z; v[3] = x0.w;
    v[4] = x1.x; v[5] = x1.y; v[6] = x1.z; v[7] = x1.w;
#pragma unroll
    for (int e = 0; e < 8; ++e) T[r][ch * 8 + e] = v[e];
    if (rhP != nullptr) {
      bf16x8 h8, l8;
#pragma unroll
      for (int e = 0; e < 8; ++e) {
        unsigned short h = f2bf(v[e]);
        h8[e] = (short)h;
        l8[e] = (short)f2bf(v[e] - bf2f(h));
      }
      size_t off = ((size_t)((i0 + r) >> 4) * 8 + (m0 >> 5) + (ch >> 2)) * 512 +
                   ((ch & 3) * 16 + (r & 15)) * 8;
      *(bf16x8*)(rhP + off) = h8;
      *(bf16x8*)(rlP + off) = l8;
    }
  }
  __syncthreads();
#pragma unroll
  for (int s = 0; s < 2; ++s) {
    int idx = tid + s * 256;
    int r = idx >> 3, c8 = idx & 7;  // out row m0+r, cols i0 + c8*8 ..
    bf16x8 h8, l8;
#pragma unroll
    for (int e = 0; e < 8; ++e) {
      float x = T[c8 * 8 + e][r];
      unsigned short h = f2bf(x);
      h8[e] = (short)h;
      l8[e] = (short)f2bf(x - bf2f(h));
    }
    size_t off = ((size_t)((m0 + r) >> 4) * 256 + (i0 >> 5) + (c8 >> 2)) * 512 +
                 ((c8 & 3) * 16 + (r & 15)) * 8;
    *(bf16x8*)(thP + off) = h8;
    *(bf16x8*)(tlP + off) = l8;
  }
}

// ---------------------------------------------------------------------------
// Stats: V-hi tile staged (packed, conflict-free); V-lo + Ap h/l packed global.
// ---------------------------------------------------------------------------
__global__ __launch_bounds__(512, 4) void stats_mfma(
    const unsigned short* __restrict__ AphP, const unsigned short* __restrict__ AplP,
    const unsigned short* __restrict__ VhP, const unsigned short* __restrict__ VlP,
    float* __restrict__ rps, float* __restrict__ cps) {
  __shared__ unsigned short Vsh[16384];  // 32 granules
  __shared__ float cred[8][64];
  const int tid = threadIdx.x;
  const int w = tid >> 6, l = tid & 63;
  const int lm = l & 15, lk = l >> 4;
  const int b = blockIdx.x;
  const int p = b >> 4, q = b & 15;

  bf16x8 ah[8];
#pragma unroll
  for (int kk = 0; kk < 8; ++kk)
    ah[kk] = ld8(AphP + ((size_t)(p * 8 + w) * 8 + kk) * 512 + l * 8);
  const unsigned short* alp = AplP + (size_t)(p * 8 + w) * 8 * 512 + l * 8;

  float rsum[4] = {0.f, 0.f, 0.f, 0.f};

  for (int jt = 0; jt < 8; ++jt) {
    const int j0 = q * 512 + jt * 64;
    const size_t gbV = (size_t)(j0 >> 4) * 8 * 512;
#pragma unroll
    for (int s = 0; s < 4; ++s) {
      int u = tid + s * 512;
      *(bf16x8*)(Vsh + u * 8) = ld8(VhP + gbV + u * 8);
    }
    __syncthreads();

    f32x4 acc[4];
#pragma unroll
    for (int js = 0; js < 4; ++js) acc[js] = f32x4{0.f, 0.f, 0.f, 0.f};
    __builtin_amdgcn_s_setprio(1);
#pragma unroll
    for (int kk = 0; kk < 8; ++kk) {
      bf16x8 alv = ld8(alp + kk * 512);
#pragma unroll
      for (int js = 0; js < 4; ++js) {
        bf16x8 bh = lds8(Vsh + (js * 8 + kk) * 512 + l * 8);
        bf16x8 bl = ld8(VlP + ((size_t)((j0 >> 4) + js) * 8 + kk) * 512 + l * 8);
        acc[js] = mfma16(ah[kk], bh, acc[js]);
        acc[js] = mfma16(ah[kk], bl, acc[js]);
        acc[js] = mfma16(alv, bh, acc[js]);
      }
    }
    __builtin_amdgcn_s_setprio(0);
#pragma unroll
    for (int js = 0; js < 4; ++js) {
      float e0 = __expf(acc[js][0] - SHIFT), e1 = __expf(acc[js][1] - SHIFT);
      float e2 = __expf(acc[js][2] - SHIFT), e3 = __expf(acc[js][3] - SHIFT);
      rsum[0] += e0; rsum[1] += e1; rsum[2] += e2; rsum[3] += e3;
      float c = e0 + e1 + e2 + e3;
      c += __shfl_xor(c, 16);
      c += __shfl_xor(c, 32);
      if (lk == 0) cred[w][js * 16 + lm] = c;
    }
    __syncthreads();
    if (tid < 64) {
      float c = 0.f;
#pragma unroll
      for (int ww = 0; ww < 8; ++ww) c += cred[ww][tid];
      cps[(size_t)p * N + j0 + tid] = c;
    }
    __syncthreads();
  }
#pragma unroll
  for (int r = 0; r < 4; ++r) {
    float s = rsum[r];
    s += __shfl_xor(s, 1);
    s += __shfl_xor(s, 2);
    s += __shfl_xor(s, 4);
    s += __shfl_xor(s, 8);
    if (lm == 0) rps[(size_t)q * N + p * 128 + w * 16 + lk * 4 + r] = s;
  }
}

__global__ void row_inv(const float* __restrict__ rps, float* __restrict__ rinv) {
  int i = blockIdx.x * 256 + threadIdx.x;
  float s = 0.f;
#pragma unroll
  for (int q = 0; q < 16; ++q) s += rps[(size_t)q * N + i];
  rinv[i] = 1.f / s;
}
__global__ void col_inv(const float* __restrict__ cps, float* __restrict__ cinv) {
  int j = blockIdx.x * 256 + threadIdx.x;
  float s = 0.f;
  for (int p = 0; p < 64; ++p) s += cps[(size_t)p * N + j];
  cinv[j] = 1.f / s;
}

// ---------------------------------------------------------------------------
// out_audio: d_audio[i,m] = sum_j E(corr[i,j])*cinv[j]*audio[j,m].
// j-tile 32. LDS 72 KB -> 2 blocks/CU (grid 512). All operands via LDS,
// staged with global_load_lds (V(t+1) issued after B2, values(t+1) after B3).
// corr wave (isub=w&3, jh=w>>2); weighted wave (isub=w&3, mhalf=w>>2).
// setprio(1) around MFMA clusters (T5: 2 blocks/CU at decorrelated phases).
// ---------------------------------------------------------------------------
__global__ __launch_bounds__(512, 4) void out_audio_p(
    const unsigned short* __restrict__ AphP, const unsigned short* __restrict__ AplP,
    const unsigned short* __restrict__ VhP, const unsigned short* __restrict__ VlP,
    const unsigned short* __restrict__ AuThP, const unsigned short* __restrict__ AuTlP,
    const float* __restrict__ cinv, float* __restrict__ out) {
  __shared__ unsigned short Vsh[8192];  // V tile [32j][256k] hi: 16 granules
  __shared__ unsigned short Vsl[8192];
  __shared__ unsigned short Ath[8192];  // AuT tile [256m][32j] hi: 16 granules
  __shared__ unsigned short Atl[8192];
  __shared__ unsigned short Wah[2048];  // W [64i][32j]: 4 granules
  __shared__ unsigned short Wal[2048];

  const int tid = threadIdx.x;
  const int w = tid >> 6, l = tid & 63;
  const int lm = l & 15, lk = l >> 4;
  const int i0 = blockIdx.x * 64;
  const int jc = blockIdx.y;  // 4 chunks of 2048
  const int isub = w & 3;
  const int jh = w >> 2;     // corr j-sub
  const int mhalf = w >> 2;  // weighted m-half

  // A fragments (hi+lo), loop-invariant: 64 VGPR
  bf16x8 ah[8], al[8];
  const size_t ab = (size_t)((i0 >> 4) + isub) * 8 * 512 + l * 8;
#pragma unroll
  for (int kk = 0; kk < 8; ++kk) {
    ah[kk] = ld8(AphP + ab + kk * 512);
    al[kk] = ld8(AplP + ab + kk * 512);
  }

  f32x4 dacc[8];
#pragma unroll
  for (int ms = 0; ms < 8; ++ms) dacc[ms] = f32x4{0.f, 0.f, 0.f, 0.f};

  auto issue_V = [&](int j0) {
    const size_t gbV = (size_t)(j0 >> 4) * 8 * 512;
#pragma unroll
    for (int s = 0; s < 2; ++s) {
      int ub = w * 64 + s * 512;  // wave-uniform granule-slot base
      gl16(VhP + gbV + (ub + l) * 8, Vsh + ub * 8);
      gl16(VlP + gbV + (ub + l) * 8, Vsl + ub * 8);
    }
  };
  auto issue_T = [&](int j0) {
#pragma unroll
    for (int s = 0; s < 2; ++s) {
      int g = w + s * 8;
      size_t srcT = ((size_t)g * 256 + (j0 >> 5)) * 512 + l * 8;
      gl16(AuThP + srcT, Ath + g * 512);
      gl16(AuTlP + srcT, Atl + g * 512);
    }
  };

  issue_V(jc * 2048);
  issue_T(jc * 2048);

  for (int jt = 0; jt < 64; ++jt) {
    const int j0 = jc * 2048 + jt * 32;
    asm volatile("s_waitcnt vmcnt(0)" ::: "memory");
    __syncthreads();  // B1: tile staged
    // ---- corr[i=i0+isub*16+lk*4+r][j=j0+jh*16+lm], 3-term ----
    f32x4 cc = f32x4{0.f, 0.f, 0.f, 0.f};
    __builtin_amdgcn_s_setprio(1);
#pragma unroll
    for (int kk = 0; kk < 8; ++kk) {
      bf16x8 bh = lds8(Vsh + (jh * 8 + kk) * 512 + l * 8);
      bf16x8 bl = lds8(Vsl + (jh * 8 + kk) * 512 + l * 8);
      cc = mfma16(ah[kk], bh, cc);
      cc = mfma16(ah[kk], bl, cc);
      cc = mfma16(al[kk], bh, cc);
    }
    __builtin_amdgcn_s_setprio(0);
    // ---- W[i_loc][j_loc] = E*cinv[j] -> packed LDS granule isub ----
    {
      float ci = cinv[j0 + jh * 16 + lm];
      size_t gb = (size_t)isub * 512 + (lm & 7);
      int lane_hi = (jh * 2 + (lm >> 3)) * 16;
#pragma unroll
      for (int r = 0; r < 4; ++r) {
        float e = __expf(cc[r] - SHIFT) * ci;
        unsigned short h = f2bf(e);
        size_t off = gb + (size_t)(lane_hi + lk * 4 + r) * 8;
        Wah[off] = h;
        Wal[off] = f2bf(e - bf2f(h));
      }
    }
    __syncthreads();  // B2: W ready; corr V reads done
    if (jt + 1 < 64) issue_V(j0 + 32);  // V(t+1) flies under weighted
    // ---- weighted: A = W granule isub, B = AuT granules (mhalf*8+ms) ----
    {
      bf16x8 wh = lds8(Wah + isub * 512 + l * 8);
      bf16x8 wl = lds8(Wal + isub * 512 + l * 8);
      __builtin_amdgcn_s_setprio(1);
#pragma unroll
      for (int ms = 0; ms < 8; ++ms) {
        bf16x8 vh8 = lds8(Ath + (mhalf * 8 + ms) * 512 + l * 8);
        bf16x8 vl8 = lds8(Atl + (mhalf * 8 + ms) * 512 + l * 8);
        dacc[ms] = mfma16(wh, vh8, dacc[ms]);
        dacc[ms] = mfma16(wh, vl8, dacc[ms]);
        dacc[ms] = mfma16(wl, vh8, dacc[ms]);
      }
      __builtin_amdgcn_s_setprio(0);
    }
    __syncthreads();  // B3: weighted reads done
    if (jt + 1 < 64) issue_T(j0 + 32);
  }
#pragma unroll
  for (int ms = 0; ms < 8; ++ms)
#pragma unroll
    for (int r = 0; r < 4; ++r) {
      int i = i0 + isub * 16 + lk * 4 + r;
      int m = mhalf * 128 + ms * 16 + lm;
      atomicAdd(out + (size_t)i * (2 * M) + M + m, dacc[ms][r]);
    }
}

// ---------------------------------------------------------------------------
// out_video: d_video[i,m] = sum_j E(corr[j,i])*rinv[j]*video[j,m].
// corr[j][i]: A = Ap[j-tile 32] (LDS h+l), B = video[i-panel] (regs, hoisted).
// corr wave (jh_c=w&1, isub_c=w>>1). weighted wave (isub=w&3, mhalf=w>>2).
// ---------------------------------------------------------------------------
__global__ __launch_bounds__(512, 4) void out_video_p(
    const unsigned short* __restrict__ AphP, const unsigned short* __restrict__ AplP,
    const unsigned short* __restrict__ VhP, const unsigned short* __restrict__ VlP,
    const unsigned short* __restrict__ ViThP, const unsigned short* __restrict__ ViTlP,
    const float* __restrict__ rinv, float* __restrict__ out) {
  __shared__ unsigned short Ash[8192];  // Ap tile [32j][256k] hi
  __shared__ unsigned short Asl[8192];
  __shared__ unsigned short Vts[8192];  // ViT tile [256m][32j] hi
  __shared__ unsigned short Vtl[8192];
  __shared__ unsigned short Wvh[2048];  // W_v [64i][32j]
  __shared__ unsigned short Wvl[2048];

  const int tid = threadIdx.x;
  const int w = tid >> 6, l = tid & 63;
  const int lm = l & 15, lk = l >> 4;
  const int i0 = blockIdx.x * 64;
  const int jc = blockIdx.y;
  const int jh_c = w & 1, isub_c = w >> 1;  // corr mapping
  const int isub = w & 3, mhalf = w >> 2;   // weighted mapping

  // hoisted video-panel B-fragments (hi+lo) for isub_c: 64 VGPR
  bf16x8 vph[8], vpl[8];
  const size_t vb = (size_t)((i0 >> 4) + isub_c) * 8 * 512 + l * 8;
#pragma unroll
  for (int kk = 0; kk < 8; ++kk) {
    vph[kk] = ld8(VhP + vb + kk * 512);
    vpl[kk] = ld8(VlP + vb + kk * 512);
  }

  f32x4 dacc[8];
#pragma unroll
  for (int ms = 0; ms < 8; ++ms) dacc[ms] = f32x4{0.f, 0.f, 0.f, 0.f};

  auto issue_A = [&](int j0) {
    const size_t gbA = (size_t)(j0 >> 4) * 8 * 512;
#pragma unroll
    for (int s = 0; s < 2; ++s) {
      int ub = w * 64 + s * 512;
      gl16(AphP + gbA + (ub + l) * 8, Ash + ub * 8);
      gl16(AplP + gbA + (ub + l) * 8, Asl + ub * 8);
    }
  };
  auto issue_T = [&](int j0) {
#pragma unroll
    for (int s = 0; s < 2; ++s) {
      int g = w + s * 8;
      size_t srcT = ((size_t)g * 256 + (j0 >> 5)) * 512 + l * 8;
      gl16(ViThP + srcT, Vts + g * 512);
      gl16(ViTlP + srcT, Vtl + g * 512);
    }
  };

  issue_A(jc * 2048);
  issue_T(jc * 2048);

  for (int jt = 0; jt < 64; ++jt) {
    const int j0 = jc * 2048 + jt * 32;
    asm volatile("s_waitcnt vmcnt(0)" ::: "memory");
    __syncthreads();  // B1
    // ---- corr[j=j0+jh_c*16+lk*4+r][i=i0+isub_c*16+lm], 3-term ----
    f32x4 cc = f32x4{0.f, 0.f, 0.f, 0.f};
    __builtin_amdgcn_s_setprio(1);
#pragma unroll
    for (int kk = 0; kk < 8; ++kk) {
      bf16x8 ahf = lds8(Ash + (jh_c * 8 + kk) * 512 + l * 8);
      bf16x8 alf = lds8(Asl + (jh_c * 8 + kk) * 512 + l * 8);
      cc = mfma16(ahf, vph[kk], cc);
      cc = mfma16(ahf, vpl[kk], cc);
      cc = mfma16(alf, vph[kk], cc);
    }
    __builtin_amdgcn_s_setprio(0);
    // ---- W_v[i_loc][j_loc] = E(corr[j][i])*rinv[j] -> granule isub_c ----
    {
#pragma unroll
      for (int r = 0; r < 4; ++r) {
        int t = lk * 4 + r;
        float e = __expf(cc[r] - SHIFT) * rinv[j0 + jh_c * 16 + t];
        unsigned short h = f2bf(e);
        size_t off = (size_t)isub_c * 512 +
                     ((size_t)((jh_c * 2 + (t >> 3)) * 16 + lm)) * 8 + (t & 7);
        Wvh[off] = h;
        Wvl[off] = f2bf(e - bf2f(h));
      }
    }
    __syncthreads();  // B2: W ready; corr Ap reads done
    if (jt + 1 < 64) issue_A(j0 + 32);
    // ---- weighted: A = W_v granule isub, B = ViT granules ----
    {
      bf16x8 wh = lds8(Wvh + isub * 512 + l * 8);
      bf16x8 wl = lds8(Wvl + isub * 512 + l * 8);
      __builtin_amdgcn_s_setprio(1);
#pragma unroll
      for (int ms = 0; ms < 8; ++ms) {
        bf16x8 vh8 = lds8(Vts + (mhalf * 8 + ms) * 512 + l * 8);
        bf16x8 vl8 = lds8(Vtl + (mhalf * 8 + ms) * 512 + l * 8);
        dacc[ms] = mfma16(wh, vh8, dacc[ms]);
        dacc[ms] = mfma16(wh, vl8, dacc[ms]);
        dacc[ms] = mfma16(wl, vh8, dacc[ms]);
      }
      __builtin_amdgcn_s_setprio(0);
    }
    __syncthreads();  // B3
    if (jt + 1 < 64) issue_T(j0 + 32);
  }
#pragma unroll
  for (int ms = 0; ms < 8; ++ms)
#pragma unroll
    for (int r = 0; r < 4; ++r) {
      int i = i0 + isub * 16 + lk * 4 + r;
      int m = mhalf * 128 + ms * 16 + lm;
      atomicAdd(out + (size_t)i * (2 * M) + m, dacc[ms][r]);
    }
}

// ---------------------------------------------------------------------------
__global__ void epilogue(float* __restrict__ out, const float* __restrict__ video,
                         const float* __restrict__ audio) {
  int idx = blockIdx.x * 256 + threadIdx.x;
  int i = idx >> 7;
  int c4 = idx & 127;
  float4 o = reinterpret_cast<float4*>(out)[(size_t)i * 128 + c4];
  const float* res = (c4 < 64) ? (video + (size_t)i * M + c4 * 4)
                               : (audio + (size_t)i * M + (c4 - 64) * 4);
  float4 rv = *reinterpret_cast<const float4*>(res);
  o.x = tanhf(o.x + rv.x);
  o.y = tanhf(o.y + rv.y);
  o.z = tanhf(o.z + rv.z);
  o.w = tanhf(o.w + rv.w);
  reinterpret_cast<float4*>(out)[(size_t)i * 128 + c4] = o;
}

// ---------------------------------------------------------------------------
extern "C" void kernel_launch(void* const* d_in, const int* in_sizes, int n_in,
                              void* d_out, int out_size, void* d_ws, size_t ws_size,
                              hipStream_t stream) {
  const float* audio = (const float*)d_in[0];
  const float* video = (const float*)d_in[1];
  const float* W = (const float*)d_in[2];
  float* out = (float*)d_out;

  const size_t nBF = (size_t)N * M * sizeof(unsigned short);  // 4 MB
  char* base = (char*)d_ws;
  unsigned short* AphP = (unsigned short*)(base);
  unsigned short* AplP = (unsigned short*)(base + 1 * nBF);
  unsigned short* VhP = (unsigned short*)(base + 2 * nBF);
  unsigned short* VlP = (unsigned short*)(base + 3 * nBF);
  unsigned short* ViThP = (unsigned short*)(base + 4 * nBF);
  unsigned short* ViTlP = (unsigned short*)(base + 5 * nBF);
  unsigned short* AuThP = (unsigned short*)(base + 6 * nBF);
  unsigned short* AuTlP = (unsigned short*)(base + 7 * nBF);
  float* rps = (float*)(base + 8 * nBF);   // 16*N
  float* cps = rps + 16 * (size_t)N;       // 64*N
  float* rinv = cps + 64 * (size_t)N;      // N
  float* cinv = rinv + N;                  // N
  const size_t need = 8 * nBF + (82 * (size_t)N) * sizeof(float);
  if (ws_size < need) return;

  zero_f32<<<dim3((N * 2 * M / 4 + 255) / 256), 256, 0, stream>>>(out, N * 2 * M / 4);
  gemm_ap<<<dim3(N / 64, M / 64), 256, 0, stream>>>(audio, W, AphP, AplP);
  trsplit<<<dim3(N / 64, M / 64), 256, 0, stream>>>(video, VhP, VlP, ViThP, ViTlP);
  trsplit<<<dim3(N / 64, M / 64), 256, 0, stream>>>(audio, nullptr, nullptr, AuThP, AuTlP);
  stats_mfma<<<1024, 512, 0, stream>>>(AphP, AplP, VhP, VlP, rps, cps);
  row_inv<<<N / 256, 256, 0, stream>>>(rps, rinv);
  col_inv<<<N / 256, 256, 0, stream>>>(cps, cinv);
  out_audio_p<<<dim3(N / 64, 4), 512, 0, stream>>>(AphP, AplP, VhP, VlP,
                                                   AuThP, AuTlP, cinv, out);
  out_video_p<<<dim3(N / 64, 4), 512, 0, stream>>>(AphP, AplP, VhP, VlP,
                                                   ViThP, ViTlP, rinv, out);
  epilogue<<<dim3(N * 2 * M / 4 / 256), 256, 0, stream>>>(out, video, audio);
}